// Round 1
// 539.765 us; speedup vs baseline: 1.0416x; 1.0416x over previous
//
#include <hip/hip_runtime.h>

#define WIN 5
#define WW 25
#define DF 64
#define DC 256
#define HF 240
#define WF 320
#define LC 4800
#define NQ 16384
#define CH_STRIDE ((size_t)HF * WF)          // 76800
#define BS_STRIDE_F ((size_t)DF * CH_STRIDE)
#define FPAD 68                 // padded LDS window row stride (17*16B aligned)

// d_ws float-index layout
#define WS_WFUSED 0                          // 256*64 floats
#define WS_BFUSED (DC * DF)                  // 64 floats (+pad)
#define WS_CPART  (DC * DF + 256)            // 32768*64 floats
#define WS_FT     (WS_CPART + 2 * NQ * DF)   // 2,113,792 -> channels-last maps
#define MAPSZ     ((size_t)4 * CH_STRIDE * DF)        // 19,660,800 floats per map
#define WS_NEEDED_BYTES (((size_t)WS_FT + 2 * MAPSZ) * 4)   // ~165.7 MB

// ---------------- K0: Wfused = Wd @ Wm_bot,  bfused = bm + bd @ Wm_bot ----
__global__ __launch_bounds__(64) void k0_fuse_weights(
    const float* __restrict__ Wd, const float* __restrict__ bd,
    const float* __restrict__ Wm, const float* __restrict__ bm,
    float* __restrict__ ws)
{
    const int r = blockIdx.x;      // 0..255 -> Wfused row; 256 -> bfused
    const int j = threadIdx.x;     // 0..63
    if (r < DC) {
        float acc = 0.f;
        #pragma unroll 8
        for (int i = 0; i < DF; ++i)
            acc += Wd[r * DF + i] * Wm[(DF + i) * DF + j];
        ws[WS_WFUSED + r * DF + j] = acc;
    } else {
        float acc = bm[j];
        #pragma unroll 8
        for (int i = 0; i < DF; ++i)
            acc += bd[i] * Wm[(DF + i) * DF + j];
        ws[WS_BFUSED + j] = acc;
    }
}

// ---------------- K1: cpart[row][j] = bfused[j] + c[row] . Wfused[:,j] -----
#define K1_ROWS 16
__global__ __launch_bounds__(256) void k1_cpart(
    const float* __restrict__ c0, const float* __restrict__ c1,
    const int* __restrict__ b_ids, const int* __restrict__ ci,
    float* __restrict__ ws)
{
    const float* __restrict__ wfused = ws + WS_WFUSED;
    const float* __restrict__ bfused = ws + WS_BFUSED;
    float* __restrict__ cpart = ws + WS_CPART;

    const int t  = threadIdx.x;
    const int j  = t & 63;         // output channel
    const int kc = t >> 6;         // K-quarter 0..3

    float wf[64];
    #pragma unroll
    for (int k = 0; k < 64; ++k)
        wf[k] = wfused[(kc * 64 + k) * DF + j];

    __shared__ float c_sh[DC];
    __shared__ float red[256];

    for (int ri = 0; ri < K1_ROWS; ++ri) {
        const int row = blockIdx.x * K1_ROWS + ri;
        const int s = row >> 14;
        const int n = row & (NQ - 1);
        const float* __restrict__ fc = s ? c1 : c0;
        const int b  = b_ids[n];
        const int cc = ci[n];

        c_sh[t] = fc[((size_t)b * LC + cc) * DC + t];   // coalesced stage
        __syncthreads();

        float acc = 0.f;
        #pragma unroll
        for (int k4 = 0; k4 < 16; ++k4) {
            float4 cv = *(const float4*)&c_sh[kc * 64 + k4 * 4];
            acc += cv.x * wf[k4 * 4 + 0] + cv.y * wf[k4 * 4 + 1] +
                   cv.z * wf[k4 * 4 + 2] + cv.w * wf[k4 * 4 + 3];
        }
        red[t] = acc;
        __syncthreads();

        if (t < 64) {
            cpart[(size_t)row * DF + t] =
                red[t] + red[t + 64] + red[t + 128] + red[t + 192] + bfused[t];
        }
    }
}

// ---------------- KT: channels-first -> channels-last transpose -----------
// in: (b, c=64, p=76800)  out: fT[b][p][c], 64x64 tiles via LDS
__global__ __launch_bounds__(256) void kt_transpose(
    const float* __restrict__ f0, const float* __restrict__ f1,
    float* __restrict__ ws)
{
    const int t = threadIdx.x;
    const float* __restrict__ src = blockIdx.z ? f1 : f0;
    float* __restrict__ fT = ws + WS_FT + (size_t)blockIdx.z * MAPSZ;
    const int b  = blockIdx.y;
    const int p0 = blockIdx.x * 64;

    __shared__ float tile[64][65];   // pad 65: 2-way (free) on both sides

    const float* __restrict__ sb = src + (size_t)b * BS_STRIDE_F;
    const int g  = t >> 4;           // 0..15
    const int x4 = t & 15;
    #pragma unroll
    for (int q = 0; q < 4; ++q) {
        const int c = g + q * 16;
        const float4 v = *(const float4*)&sb[(size_t)c * CH_STRIDE + p0 + x4 * 4];
        tile[c][x4 * 4 + 0] = v.x; tile[c][x4 * 4 + 1] = v.y;
        tile[c][x4 * 4 + 2] = v.z; tile[c][x4 * 4 + 3] = v.w;
    }
    __syncthreads();
    float* __restrict__ ob = fT + ((size_t)b * CH_STRIDE + p0) * DF;
    #pragma unroll
    for (int q = 0; q < 4; ++q) {
        const int p  = g + q * 16;
        const int cc = x4 * 4;
        const float4 v = make_float4(tile[cc + 0][p], tile[cc + 1][p],
                                     tile[cc + 2][p], tile[cc + 3][p]);
        *(float4*)&ob[(size_t)p * DF + cc] = v;
    }
}

// ---------------- K2T: main — gather from channels-last fT ----------------
__global__ __launch_bounds__(256) void k2_main_t(
    const float* __restrict__ Wm,
    const int* __restrict__ b_ids, const int* __restrict__ cy,
    const int* __restrict__ cx,
    const float* __restrict__ ws, float* __restrict__ out)
{
    const float* __restrict__ cpart = ws + WS_CPART;

    const int t    = threadIdx.x;
    const int lane = t & 63;
    const int wave = t >> 6;

    __shared__ float wm_sh[DF * DF];            // Wm top half, 16 KB
    __shared__ float f_sh[4 * WW * FPAD];       // per-wave window tiles, 27.2 KB

    // ---- stage Wm[0:64] (block-cooperative, coalesced float4) ----
    {
        const float4* src = (const float4*)Wm;
        float4* dst = (float4*)wm_sh;
        #pragma unroll
        for (int q = 0; q < 4; ++q)
            dst[t + q * 256] = src[t + q * 256];
    }

    // ---- wave-private window gather: 7 coalesced float4 wave-loads ----
    const int gw = blockIdx.x * 4 + wave;       // 0..32767 = s*NQ + n
    const int s  = gw >> 14;
    const int n  = gw & (NQ - 1);
    const float* __restrict__ fT = ws + WS_FT + (size_t)s * MAPSZ;
    const int b = b_ids[n];
    const int Y = cy[n];
    const int X = cx[n];

    float* fw = f_sh + wave * WW * FPAD;
    const float* __restrict__ wbase =
        fT + ((size_t)(b * HF + (Y - 2)) * WF + (X - 2)) * DF;
    #pragma unroll
    for (int r = 0; r < 7; ++r) {
        const int e = lane + r * 64;            // float4 index: 0..399
        if (e < 400) {
            const int w  = e >> 4;              // window pos 0..24
            const int i4 = e & 15;              // channel quad
            const int wy = (w * 13) >> 6;       // w/5 for w<25
            const int wx = w - wy * 5;
            const float4 v =
                *(const float4*)&wbase[(size_t)(wy * WF + wx) * DF + i4 * 4];
            // bank = (4w + 4*i4) % 32 -> exactly 8 accesses/bank = minimum
            *(float4*)&fw[w * FPAD + i4 * 4] = v;
        }
    }
    __syncthreads();

    // ---- compute: out[w][j] = cpart[j] + sum_i f[w][i]*wm[i][j] ----
    const int j0 = (lane & 15) * 4;             // 4 output channels
    const int w0 = lane >> 4;                   // window group: w = w0 + 4u

    const float4 cp = *(const float4*)&cpart[(size_t)gw * DF + j0];
    float4 acc[7];
    #pragma unroll
    for (int u = 0; u < 7; ++u) acc[u] = cp;

    #pragma unroll 4
    for (int i = 0; i < DF; i += 4) {
        const float4 m0 = *(const float4*)&wm_sh[(i + 0) * DF + j0];
        const float4 m1 = *(const float4*)&wm_sh[(i + 1) * DF + j0];
        const float4 m2 = *(const float4*)&wm_sh[(i + 2) * DF + j0];
        const float4 m3 = *(const float4*)&wm_sh[(i + 3) * DF + j0];
        #pragma unroll
        for (int u = 0; u < 7; ++u) {
            // address clamp instead of exec-mask guard; u=6 w0>0 lanes
            // recompute w=24 (broadcast, free) and are discarded at store
            const int w = (w0 + 4 * u < WW) ? (w0 + 4 * u) : (WW - 1);
            const float4 fv = *(const float4*)&fw[w * FPAD + i];
            acc[u].x += fv.x * m0.x + fv.y * m1.x + fv.z * m2.x + fv.w * m3.x;
            acc[u].y += fv.x * m0.y + fv.y * m1.y + fv.z * m2.y + fv.w * m3.y;
            acc[u].z += fv.x * m0.z + fv.y * m1.z + fv.z * m2.z + fv.w * m3.z;
            acc[u].w += fv.x * m0.w + fv.y * m1.w + fv.z * m2.w + fv.w * m3.w;
        }
    }

    // ---- store ----
    float* ob = out + (size_t)gw * (WW * DF);
    #pragma unroll
    for (int u = 0; u < 7; ++u) {
        const int w = w0 + 4 * u;
        if (w < WW)
            *(float4*)&ob[w * DF + j0] = acc[u];
    }
}

// ---------------- K2 (fallback): original gather from channels-first ------
__global__ __launch_bounds__(256) void k2_main(
    const float* __restrict__ f0, const float* __restrict__ f1,
    const float* __restrict__ Wm,
    const int* __restrict__ b_ids, const int* __restrict__ cy,
    const int* __restrict__ cx,
    const float* __restrict__ ws, float* __restrict__ out)
{
    const float* __restrict__ cpart = ws + WS_CPART;

    const int t    = threadIdx.x;
    const int lane = t & 63;
    const int wave = t >> 6;

    __shared__ float wm_sh[DF * DF];
    __shared__ float f_sh[4 * WW * FPAD];

    {
        const float4* src = (const float4*)Wm;
        float4* dst = (float4*)wm_sh;
        #pragma unroll
        for (int q = 0; q < 4; ++q)
            dst[t + q * 256] = src[t + q * 256];
    }

    const int gw = blockIdx.x * 4 + wave;
    const int s  = gw >> 14;
    const int n  = gw & (NQ - 1);
    const float* __restrict__ ff = s ? f1 : f0;
    const int b = b_ids[n];
    const int Y = cy[n];
    const int X = cx[n];

    float* fw = f_sh + wave * WW * FPAD;
    const float* fwin = ff + (size_t)b * BS_STRIDE_F + (size_t)(Y - 2) * WF + (X - 2);
    #pragma unroll
    for (int r = 0; r < 25; ++r) {
        const int e = lane + r * 64;
        const int i = e / 25;
        const int w = e - i * 25;
        const int wy = w / 5;
        const int wx = w - wy * 5;
        fw[w * FPAD + i] = fwin[(size_t)i * CH_STRIDE + wy * WF + wx];
    }
    __syncthreads();

    const int j0 = (lane & 15) * 4;
    const int w0 = lane >> 4;

    const float4 cp = *(const float4*)&cpart[(size_t)gw * DF + j0];
    float4 acc[7];
    #pragma unroll
    for (int u = 0; u < 7; ++u) acc[u] = cp;

    #pragma unroll 4
    for (int i = 0; i < DF; i += 4) {
        const float4 m0 = *(const float4*)&wm_sh[(i + 0) * DF + j0];
        const float4 m1 = *(const float4*)&wm_sh[(i + 1) * DF + j0];
        const float4 m2 = *(const float4*)&wm_sh[(i + 2) * DF + j0];
        const float4 m3 = *(const float4*)&wm_sh[(i + 3) * DF + j0];
        #pragma unroll
        for (int u = 0; u < 7; ++u) {
            const int w = w0 + 4 * u;
            if (w < WW) {
                const float4 fv = *(const float4*)&fw[w * FPAD + i];
                acc[u].x += fv.x * m0.x + fv.y * m1.x + fv.z * m2.x + fv.w * m3.x;
                acc[u].y += fv.x * m0.y + fv.y * m1.y + fv.z * m2.y + fv.w * m3.y;
                acc[u].z += fv.x * m0.z + fv.y * m1.z + fv.z * m2.z + fv.w * m3.z;
                acc[u].w += fv.x * m0.w + fv.y * m1.w + fv.z * m2.w + fv.w * m3.w;
            }
        }
    }

    float* ob = out + (size_t)gw * (WW * DF);
    #pragma unroll
    for (int u = 0; u < 7; ++u) {
        const int w = w0 + 4 * u;
        if (w < WW)
            *(float4*)&ob[w * DF + j0] = acc[u];
    }
}

extern "C" void kernel_launch(void* const* d_in, const int* in_sizes, int n_in,
                              void* d_out, int out_size, void* d_ws, size_t ws_size,
                              hipStream_t stream) {
    const float* f0 = (const float*)d_in[0];
    const float* f1 = (const float*)d_in[1];
    const float* c0 = (const float*)d_in[2];
    const float* c1 = (const float*)d_in[3];
    const float* Wd = (const float*)d_in[4];
    const float* bd = (const float*)d_in[5];
    const float* Wm = (const float*)d_in[6];
    const float* bm = (const float*)d_in[7];
    const int* b_ids = (const int*)d_in[8];
    const int* cyv   = (const int*)d_in[9];
    const int* cxv   = (const int*)d_in[10];
    const int* civ   = (const int*)d_in[11];
    float* out = (float*)d_out;
    float* ws  = (float*)d_ws;

    const bool big_ws = (ws_size >= WS_NEEDED_BYTES);

    if (big_ws) {
        // channels-last staging (157 MB in ws), then fully-coalesced gather
        kt_transpose<<<dim3(CH_STRIDE / 64, 4, 2), dim3(256), 0, stream>>>(f0, f1, ws);
    }
    k0_fuse_weights<<<dim3(DC + 1), dim3(64), 0, stream>>>(Wd, bd, Wm, bm, ws);
    k1_cpart<<<dim3(2 * NQ / K1_ROWS), dim3(256), 0, stream>>>(c0, c1, b_ids, civ, ws);
    if (big_ws) {
        k2_main_t<<<dim3(2 * NQ / 4), dim3(256), 0, stream>>>(
            Wm, b_ids, cyv, cxv, ws, out);
    } else {
        k2_main<<<dim3(2 * NQ / 4), dim3(256), 0, stream>>>(
            f0, f1, Wm, b_ids, cyv, cxv, ws, out);
    }
}